// Round 1
// baseline (529.878 us; speedup 1.0000x reference)
//
#include <hip/hip_runtime.h>
#include <math.h>

#define EPS 1e-8

constexpr int CSPLIT = 16;  // channel split for pass-1 occupancy (512 blocks/b)
constexpr int CH = 1024;    // t-chunk length for the hierarchical scan (= 256 float4)

// Pass 1 (per batch b): partial column sums/sumsq over C/CSPLIT channels.
// float4 along t: 16 B/lane loads. Layout: psum[s][t], psumsq[s][t] as float4.
__global__ __launch_bounds__(256) void clnorm_colsum_b(
    const float4* __restrict__ x4, float4* __restrict__ psum4,
    float4* __restrict__ psumsq4, int b, int C, int T4) {
  int t4 = blockIdx.x * 256 + threadIdx.x;
  if (t4 >= T4) return;
  int s = blockIdx.y;
  int cPer = C / CSPLIT;
  const float4* xp = x4 + ((size_t)b * C + (size_t)s * cPer) * (size_t)T4 + t4;
  float4 sum = make_float4(0.f, 0.f, 0.f, 0.f);
  float4 sq = make_float4(0.f, 0.f, 0.f, 0.f);
#pragma unroll 8
  for (int c = 0; c < cPer; ++c) {
    float4 v = xp[(size_t)c * T4];
    sum.x += v.x;
    sum.y += v.y;
    sum.z += v.z;
    sum.w += v.w;
    sq.x = fmaf(v.x, v.x, sq.x);
    sq.y = fmaf(v.y, v.y, sq.y);
    sq.z = fmaf(v.z, v.z, sq.z);
    sq.w = fmaf(v.w, v.w, sq.w);
  }
  size_t o = (size_t)s * T4 + t4;
  psum4[o] = sum;
  psumsq4[o] = sq;
}

// Pass 2a (per b): per-chunk totals of (sum, sumsq) in double.
// One block per chunk of 1024 t (= 256 float4). chunkTot[ch*2 + {0,1}]
__global__ __launch_bounds__(256) void clnorm_chunktot_b(
    const float4* __restrict__ psum4, const float4* __restrict__ psumsq4,
    double* __restrict__ chunkTot, int T4) {
  int ch = blockIdx.x;
  int tid = threadIdx.x;
  int t4 = ch * 256 + tid;
  double ls = 0.0, lq = 0.0;
  if (t4 < T4) {
#pragma unroll
    for (int k = 0; k < CSPLIT; ++k) {
      float4 s4 = psum4[(size_t)k * T4 + t4];
      float4 q4 = psumsq4[(size_t)k * T4 + t4];
      ls += (double)((s4.x + s4.y) + (s4.z + s4.w));
      lq += (double)((q4.x + q4.y) + (q4.z + q4.w));
    }
  }
  __shared__ double sh_s[256];
  __shared__ double sh_q[256];
  sh_s[tid] = ls;
  sh_q[tid] = lq;
  __syncthreads();
  for (int off = 128; off > 0; off >>= 1) {
    if (tid < off) {
      sh_s[tid] += sh_s[tid + off];
      sh_q[tid] += sh_q[tid + off];
    }
    __syncthreads();
  }
  if (tid == 0) {
    chunkTot[(size_t)ch * 2 + 0] = sh_s[0];
    chunkTot[(size_t)ch * 2 + 1] = sh_q[0];
  }
}

// Pass 2b (per b): offset from preceding chunk totals, in-block inclusive scan,
// emit mean & rstd (float4 writes). Per-thread 4 elements live in registers.
__global__ __launch_bounds__(256) void clnorm_scanemit_b(
    const float4* __restrict__ psum4, const float4* __restrict__ psumsq4,
    const double* __restrict__ chunkTot, float* __restrict__ mean,
    float* __restrict__ rstd, int b, int C, int T, int nCh) {
  int ch = blockIdx.x;
  int tid = threadIdx.x;
  int T4 = T / 4;
  int t4 = ch * 256 + tid;

  __shared__ double tp_s[256];
  __shared__ double tp_q[256];
  __shared__ double off_sq[2];

  if (tid == 0) {
    double os = 0.0, oq = 0.0;
    for (int c0 = 0; c0 < ch; ++c0) {
      os += chunkTot[(size_t)c0 * 2 + 0];
      oq += chunkTot[(size_t)c0 * 2 + 1];
    }
    off_sq[0] = os;
    off_sq[1] = oq;
  }

  // this thread's 4 contiguous t-elements, accumulated over CSPLIT in double
  double ds[4] = {0.0, 0.0, 0.0, 0.0};
  double dq[4] = {0.0, 0.0, 0.0, 0.0};
  if (t4 < T4) {
#pragma unroll
    for (int k = 0; k < CSPLIT; ++k) {
      float4 s4 = psum4[(size_t)k * T4 + t4];
      float4 q4 = psumsq4[(size_t)k * T4 + t4];
      ds[0] += (double)s4.x;
      ds[1] += (double)s4.y;
      ds[2] += (double)s4.z;
      ds[3] += (double)s4.w;
      dq[0] += (double)q4.x;
      dq[1] += (double)q4.y;
      dq[2] += (double)q4.z;
      dq[3] += (double)q4.w;
    }
  }
  double ts = (ds[0] + ds[1]) + (ds[2] + ds[3]);
  double tq = (dq[0] + dq[1]) + (dq[2] + dq[3]);
  tp_s[tid] = ts;
  tp_q[tid] = tq;
  __syncthreads();
  // Hillis-Steele inclusive scan over 256 thread totals
  for (int off = 1; off < 256; off <<= 1) {
    double vs = (tid >= off) ? tp_s[tid - off] : 0.0;
    double vq = (tid >= off) ? tp_q[tid - off] : 0.0;
    __syncthreads();
    tp_s[tid] += vs;
    tp_q[tid] += vq;
    __syncthreads();
  }
  double run_s = off_sq[0] + tp_s[tid] - ts;  // chunk offset + exclusive prefix
  double run_q = off_sq[1] + tp_q[tid] - tq;

  int t0 = t4 * 4;
  float m_out[4], r_out[4];
#pragma unroll
  for (int j = 0; j < 4; ++j) {
    run_s += ds[j];
    run_q += dq[j];
    double cnt = (double)(t0 + j + 1) * (double)C;
    double m = run_s / cnt;
    double var = run_q / cnt - m * m;
    if (var < 0.0) var = 0.0;
    m_out[j] = (float)m;
    r_out[j] = (float)(1.0 / sqrt(var + EPS));
  }
  if (t0 < T) {  // T % 4 == 0, so full float4 write is safe
    size_t mo = (size_t)b * T + t0;
    *(float4*)(mean + mo) = make_float4(m_out[0], m_out[1], m_out[2], m_out[3]);
    *(float4*)(rstd + mo) = make_float4(r_out[0], r_out[1], r_out[2], r_out[3]);
  }
}

// Pass 3 (per b): y = (x - mean[t]) * rstd[t] * w[c] + bias[c], float4 along t.
// x[b] slab (65.5 MB) was just streamed by pass 1 -> read hits Infinity Cache.
__global__ __launch_bounds__(256) void clnorm_apply_b(
    const float4* __restrict__ x4, const float* __restrict__ w,
    const float* __restrict__ bias, const float4* __restrict__ mean4,
    const float4* __restrict__ rstd4, float4* __restrict__ y4,
    int b, int C, int T4) {
  int t4 = blockIdx.x * 256 + threadIdx.x;
  if (t4 >= T4) return;
  int c = blockIdx.y;
  size_t id = ((size_t)b * C + c) * (size_t)T4 + t4;
  size_t mo = (size_t)b * T4 + t4;
  float4 xv = x4[id];
  float4 mv = mean4[mo];
  float4 rv = rstd4[mo];
  float wc = w[c];
  float bc = bias[c];
  float4 yv;
  yv.x = (xv.x - mv.x) * rv.x * wc + bc;
  yv.y = (xv.y - mv.y) * rv.y * wc + bc;
  yv.z = (xv.z - mv.z) * rv.z * wc + bc;
  yv.w = (xv.w - mv.w) * rv.w * wc + bc;
  y4[id] = yv;
}

extern "C" void kernel_launch(void* const* d_in, const int* in_sizes, int n_in,
                              void* d_out, int out_size, void* d_ws,
                              size_t ws_size, hipStream_t stream) {
  const float* x = (const float*)d_in[0];
  const float* w = (const float*)d_in[1];
  const float* bias = (const float*)d_in[2];
  float* out = (float*)d_out;

  const int B = 4;                // from reference setup_inputs
  int C = in_sizes[1];            // 512
  int T = in_sizes[0] / (B * C);  // 32000
  int T4 = T / 4;
  int nCh = (T + CH - 1) / CH;    // 32

  // Workspace layout (floats): psum[CSPLIT*T] | psumsq[CSPLIT*T] |
  //   mean[B*T] | rstd[B*T] | chunkTot (nCh*2 doubles, 16B-aligned offset)
  float* ws = (float*)d_ws;
  size_t pn = (size_t)CSPLIT * T;
  float* psum = ws;
  float* psumsq = psum + pn;
  float* mean = psumsq + pn;
  float* rstd = mean + (size_t)B * T;
  double* chunkTot = (double*)(rstd + (size_t)B * T);

  dim3 gc((T4 + 255) / 256, CSPLIT);  // 32 x 16 = 512 blocks per b
  dim3 g2(nCh);                       // 32 blocks
  dim3 ga((T4 + 255) / 256, C);       // 32 x 512 = 16384 blocks per b

  // Per-batch chain: the 65.5 MB x[b] slab streamed by colsum_b stays resident
  // in the 256 MB Infinity Cache, so apply_b's re-read avoids HBM.
  for (int b = 0; b < B; ++b) {
    clnorm_colsum_b<<<gc, 256, 0, stream>>>((const float4*)x, (float4*)psum,
                                            (float4*)psumsq, b, C, T4);
    clnorm_chunktot_b<<<g2, 256, 0, stream>>>((const float4*)psum,
                                              (const float4*)psumsq, chunkTot,
                                              T4);
    clnorm_scanemit_b<<<g2, 256, 0, stream>>>((const float4*)psum,
                                              (const float4*)psumsq, chunkTot,
                                              mean, rstd, b, C, T, nCh);
    clnorm_apply_b<<<ga, 256, 0, stream>>>((const float4*)x, w, bias,
                                           (const float4*)mean,
                                           (const float4*)rstd, (float4*)out,
                                           b, C, T4);
  }
}